// Round 1
// baseline (348.778 us; speedup 1.0000x reference)
//
#include <hip/hip_runtime.h>
#include <math.h>

#define KOBJ 512

__device__ __forceinline__ float wave_red_f(float v) {
  #pragma unroll
  for (int off = 32; off > 0; off >>= 1) v += __shfl_down(v, off, 64);
  return v;
}
__device__ __forceinline__ int wave_red_i(int v) {
  #pragma unroll
  for (int off = 32; off > 0; off >>= 1) v += __shfl_down(v, off, 64);
  return v;
}

__global__ void k_zero(unsigned* __restrict__ p, int n) {
  int i = blockIdx.x * blockDim.x + threadIdx.x;
  if (i < n) p[i] = 0u;
}

// Per-hit pass: q, per-object argmax(q) via packed atomicMax, object counts,
// payload losses (masked), noise sums.
__global__ void k_prep(const float* __restrict__ beta, const int* __restrict__ oid,
                       const float* __restrict__ energy, const float* __restrict__ eph,
                       const float* __restrict__ mom, const float* __restrict__ mph,
                       const float* __restrict__ logits, const int* __restrict__ pid,
                       float* __restrict__ qbuf, unsigned long long* __restrict__ amax,
                       unsigned* __restrict__ att_cnt, float* __restrict__ acc,
                       unsigned* __restrict__ uacc, int n) {
  int i = blockIdx.x * blockDim.x + threadIdx.x;
  float e_t = 0.f, p_t = 0.f, pid_t = 0.f, noise_t = 0.f;
  int ncnt = 0, mc = 0;
  if (i < n) {
    float b = beta[i];
    float a = atanhf(b);
    float q = fmaf(a, a, 1.0f);
    qbuf[i] = q;
    int o = oid[i];
    if (o > 0) {
      // pack: (q bits)<<32 | ~i  -> max picks max-q, ties pick smallest i (argmax semantics)
      unsigned long long key = ((unsigned long long)__float_as_uint(q) << 32)
                             | (unsigned long long)(unsigned)(~(unsigned)i);
      atomicMax(&amax[o - 1], key);
      atomicAdd(&att_cnt[o - 1], 1u);
      mc = 1;
      float de = energy[i] - eph[i];
      e_t = de * de;
      float p0 = mom[3*i+0] - mph[3*i+0];
      float p1 = mom[3*i+1] - mph[3*i+1];
      float p2 = mom[3*i+2] - mph[3*i+2];
      p_t = p0*p0 + p1*p1 + p2*p2;
      const float* lg = logits + 6*i;
      float mx = lg[0];
      #pragma unroll
      for (int c = 1; c < 6; c++) mx = fmaxf(mx, lg[c]);
      float s = 0.f;
      #pragma unroll
      for (int c = 0; c < 6; c++) s += expf(lg[c] - mx);
      pid_t = mx + logf(s) - lg[pid[i]];
    } else {
      noise_t = b;
      ncnt = 1;
    }
  }
  e_t = wave_red_f(e_t);
  p_t = wave_red_f(p_t);
  pid_t = wave_red_f(pid_t);
  noise_t = wave_red_f(noise_t);
  ncnt = wave_red_i(ncnt);
  mc = wave_red_i(mc);
  if ((threadIdx.x & 63) == 0) {
    atomicAdd(&acc[3], noise_t);
    atomicAdd(&acc[4], e_t);
    atomicAdd(&acc[5], p_t);
    atomicAdd(&acc[6], pid_t);
    atomicAdd(&uacc[0], (unsigned)ncnt);
    atomicAdd(&uacc[1], (unsigned)mc);
  }
}

// Decode condensation points, build per-object tables.
__global__ void k_gather(const float* __restrict__ x, const float* __restrict__ beta,
                         const unsigned long long* __restrict__ amax,
                         const unsigned* __restrict__ att_cnt,
                         float* __restrict__ xk, float* __restrict__ xk2,
                         float* __restrict__ qk, float* __restrict__ inv_att,
                         float* __restrict__ inv_nrep, float* __restrict__ acc, int n) {
  int k = blockIdx.x * blockDim.x + threadIdx.x;
  float cow = 0.f;
  if (k < KOBJ) {
    unsigned long long key = amax[k];
    unsigned idx = ~(unsigned)(key & 0xffffffffull);
    float s2 = 0.f;
    #pragma unroll
    for (int c = 0; c < 8; c++) {
      float v = x[(size_t)idx * 8 + c];
      xk[k * 8 + c] = v;
      s2 = fmaf(v, v, s2);
    }
    xk2[k] = s2;
    qk[k] = __uint_as_float((unsigned)(key >> 32));
    unsigned cnt = att_cnt[k];
    inv_att[k] = 1.0f / ((float)cnt + 1e-9f);
    inv_nrep[k] = 1.0f / ((float)(n - (int)cnt) + 1e-9f);
    cow = 1.0f - beta[idx];
  }
  cow = wave_red_f(cow);
  if ((threadIdx.x & 63) == 0) atomicAdd(&acc[2], cow);
}

// Hot kernel: every thread = one hit, loop over all 512 objects in LDS.
__global__ __launch_bounds__(256) void
k_pairs(const float* __restrict__ x, const int* __restrict__ oid,
        const float* __restrict__ qbuf, const float* __restrict__ xk,
        const float* __restrict__ xk2, const float* __restrict__ qk,
        const float* __restrict__ inv_att, const float* __restrict__ inv_nrep,
        float* __restrict__ acc, unsigned* __restrict__ uacc, int n) {
  __shared__ float s_xk[KOBJ * 8];
  __shared__ float s_xk2[KOBJ];
  __shared__ float s_qk[KOBJ];
  __shared__ float s_invr[KOBJ];
  for (int t = threadIdx.x; t < KOBJ * 8; t += 256) s_xk[t] = xk[t];
  for (int t = threadIdx.x; t < KOBJ; t += 256) {
    s_xk2[t] = xk2[t];
    s_qk[t] = qk[t];
    s_invr[t] = inv_nrep[t];
  }
  __syncthreads();

  int i = blockIdx.x * blockDim.x + threadIdx.x;
  float att = 0.f, rep = 0.f;
  int nrep = 0;
  if (i < n) {
    const float4* xp = (const float4*)x;
    float4 xa = xp[2 * i];
    float4 xb = xp[2 * i + 1];
    float xi[8] = {xa.x, xa.y, xa.z, xa.w, xb.x, xb.y, xb.z, xb.w};
    float xi2 = 0.f;
    #pragma unroll
    for (int c = 0; c < 8; c++) xi2 = fmaf(xi[c], xi[c], xi2);
    float qi = qbuf[i];
    int own = oid[i] - 1;  // -1 for noise

    if (own >= 0) {
      float dot = 0.f;
      #pragma unroll
      for (int c = 0; c < 8; c++) dot = fmaf(xi[c], s_xk[own * 8 + c], dot);
      float d2 = fmaxf(xi2 + s_xk2[own] - 2.f * dot, 0.f);
      att = qi * s_qk[own] * d2 * inv_att[own];
    }

    #pragma unroll 4
    for (int k = 0; k < KOBJ; k++) {
      float dot = 0.f;
      #pragma unroll
      for (int c = 0; c < 8; c++) dot = fmaf(xi[c], s_xk[k * 8 + c], dot);
      float d2 = xi2 + s_xk2[k] - 2.f * dot;
      // dist<1 <=> d2<1 (incl. negative d2); sqrt only on the rare hit
      if (d2 < 1.0f && k != own) {
        float dc = fmaxf(d2, 0.f);
        float dist = sqrtf(fmaxf(dc, 1e-12f));
        rep = fmaf(qi * s_qk[k] * (1.0f - dist), s_invr[k], rep);
        nrep++;
      }
    }
  }
  att = wave_red_f(att);
  rep = wave_red_f(rep);
  nrep = wave_red_i(nrep);
  if ((threadIdx.x & 63) == 0) {
    atomicAdd(&acc[0], att);
    atomicAdd(&acc[1], rep);
    atomicAdd(&uacc[2], (unsigned)nrep);
  }
}

__global__ void k_finalize(const float* __restrict__ acc, const unsigned* __restrict__ uacc,
                           float* __restrict__ out) {
  if (threadIdx.x == 0 && blockIdx.x == 0) {
    float v_att = acc[0] / (float)KOBJ;
    float v_rep = acc[1] / (float)KOBJ;
    float l_cow = acc[2] / (float)KOBJ;
    float l_noise = acc[3] / (float)uacc[0];
    float n_rep = (float)uacc[2];
    float oc = v_att + v_rep + l_cow + l_noise;
    float nm = (float)uacc[1];
    float e_loss = acc[4] / nm;
    float p_loss = acc[5] / (nm * 3.0f);
    float pid_loss = acc[6] / nm;
    out[0] = v_att;
    out[1] = v_rep;
    out[2] = l_cow;
    out[3] = l_noise;
    out[4] = n_rep;
    out[5] = oc;
    out[6] = e_loss;
    out[7] = p_loss;
    out[8] = pid_loss;
    out[9] = oc + e_loss + p_loss + pid_loss;
  }
}

extern "C" void kernel_launch(void* const* d_in, const int* in_sizes, int n_in,
                              void* d_out, int out_size, void* d_ws, size_t ws_size,
                              hipStream_t stream) {
  const float* beta   = (const float*)d_in[0];
  const float* x      = (const float*)d_in[1];
  const int*   oid    = (const int*)d_in[2];
  const float* energy = (const float*)d_in[3];
  const float* eph    = (const float*)d_in[4];
  const float* mom    = (const float*)d_in[5];
  const float* mph    = (const float*)d_in[6];
  const float* logits = (const float*)d_in[7];
  const int*   pid    = (const int*)d_in[8];
  float* out = (float*)d_out;
  const int n = in_sizes[0];

  char* base = (char*)d_ws;
  size_t off = 0;
  float* qbuf = (float*)(base + off);
  off += (size_t)n * 4;
  off = (off + 255) & ~(size_t)255;
  // zero-needed region starts here
  size_t zstart = off;
  unsigned long long* amax = (unsigned long long*)(base + off); off += KOBJ * 8;
  unsigned* att_cnt = (unsigned*)(base + off);                  off += KOBJ * 4;
  float* acc = (float*)(base + off);                            off += 8 * 4;
  unsigned* uacc = (unsigned*)(base + off);                     off += 8 * 4;
  size_t zend = off;
  // non-zeroed tables (fully written by k_gather)
  float* xk       = (float*)(base + off); off += KOBJ * 8 * 4;
  float* xk2      = (float*)(base + off); off += KOBJ * 4;
  float* qk       = (float*)(base + off); off += KOBJ * 4;
  float* inv_att  = (float*)(base + off); off += KOBJ * 4;
  float* inv_nrep = (float*)(base + off); off += KOBJ * 4;

  int zcount = (int)((zend - zstart) / 4);
  int nblk = (n + 255) / 256;

  k_zero<<<(zcount + 255) / 256, 256, 0, stream>>>((unsigned*)(base + zstart), zcount);
  k_prep<<<nblk, 256, 0, stream>>>(beta, oid, energy, eph, mom, mph, logits, pid,
                                   qbuf, amax, att_cnt, acc, uacc, n);
  k_gather<<<(KOBJ + 255) / 256, 256, 0, stream>>>(x, beta, amax, att_cnt, xk, xk2, qk,
                                                   inv_att, inv_nrep, acc, n);
  k_pairs<<<nblk, 256, 0, stream>>>(x, oid, qbuf, xk, xk2, qk, inv_att, inv_nrep,
                                    acc, uacc, n);
  k_finalize<<<1, 64, 0, stream>>>(acc, uacc, out);
}

// Round 2
// 143.568 us; speedup vs baseline: 2.4294x; 2.4294x over previous
//
#include <hip/hip_runtime.h>
#include <math.h>

#define KOBJ 512
#define MPREP 64
#define KTW 12   // packed per-object row: x[8], xk2, qk, qk*inv_nrep, qk*inv_att

__device__ __forceinline__ float wave_red_f(float v) {
  #pragma unroll
  for (int off = 32; off > 0; off >>= 1) v += __shfl_down(v, off, 64);
  return v;
}

// fast atanh(b)^2 + 1 ; b in (0, 0.96]
__device__ __forceinline__ float q_of_beta(float b) {
  float a = 0.5f * __logf((1.f + b) / (1.f - b));
  return fmaf(a, a, 1.f);
}

// ---------------------------------------------------------------------------
// Pass 1: 64 persistent blocks. LDS-aggregated per-object argmax(q) / counts,
// flushed as per-block partial tables (plain stores). Payload losses reduced
// per block (plain store). ZERO global atomics.
// ---------------------------------------------------------------------------
__global__ __launch_bounds__(256) void
k_prep(const float* __restrict__ beta, const int* __restrict__ oid,
       const float* __restrict__ energy, const float* __restrict__ eph,
       const float* __restrict__ mom, const float* __restrict__ mph,
       const float* __restrict__ logits, const int* __restrict__ pid,
       unsigned long long* __restrict__ amax_part,
       unsigned* __restrict__ cnt_part,
       float* __restrict__ scal_part, int n) {
  __shared__ unsigned long long lmax[KOBJ];
  __shared__ unsigned lcnt[KOBJ];
  for (int t = threadIdx.x; t < KOBJ; t += 256) { lmax[t] = 0ull; lcnt[t] = 0u; }
  __syncthreads();

  float e_t = 0.f, p_t = 0.f, pid_t = 0.f, noise_t = 0.f, ncnt = 0.f, mcnt = 0.f;
  for (int i = blockIdx.x * 256 + threadIdx.x; i < n; i += MPREP * 256) {
    float b = beta[i];
    int o = oid[i];
    if (o > 0) {
      float q = q_of_beta(b);
      // pack (q bits | ~i): max-q wins, ties -> smallest index (argmax semantics)
      unsigned long long key = ((unsigned long long)__float_as_uint(q) << 32)
                             | (unsigned long long)(unsigned)(~(unsigned)i);
      atomicMax(&lmax[o - 1], key);
      atomicAdd(&lcnt[o - 1], 1u);
      mcnt += 1.f;
      float de = energy[i] - eph[i];
      e_t = fmaf(de, de, e_t);
      float p0 = mom[3*i+0] - mph[3*i+0];
      float p1 = mom[3*i+1] - mph[3*i+1];
      float p2 = mom[3*i+2] - mph[3*i+2];
      p_t = fmaf(p0, p0, p_t); p_t = fmaf(p1, p1, p_t); p_t = fmaf(p2, p2, p_t);
      const float* lg = logits + 6*i;
      float l0=lg[0], l1=lg[1], l2=lg[2], l3=lg[3], l4=lg[4], l5=lg[5];
      float mx = fmaxf(fmaxf(fmaxf(l0,l1),fmaxf(l2,l3)), fmaxf(l4,l5));
      float s = __expf(l0-mx)+__expf(l1-mx)+__expf(l2-mx)
              + __expf(l3-mx)+__expf(l4-mx)+__expf(l5-mx);
      int pc = pid[i];
      float lp = (pc==0)?l0:(pc==1)?l1:(pc==2)?l2:(pc==3)?l3:(pc==4)?l4:l5;
      pid_t += mx + __logf(s) - lp;
    } else {
      noise_t += b;
      ncnt += 1.f;
    }
  }
  __syncthreads();

  // flush partial tables (coalesced plain stores)
  for (int t = threadIdx.x; t < KOBJ; t += 256) {
    amax_part[(size_t)blockIdx.x * KOBJ + t] = lmax[t];
    cnt_part[(size_t)blockIdx.x * KOBJ + t]  = lcnt[t];
  }

  // block-reduce the 6 scalars, one plain store
  float vals[6] = {e_t, p_t, pid_t, noise_t, ncnt, mcnt};
  #pragma unroll
  for (int j = 0; j < 6; j++) vals[j] = wave_red_f(vals[j]);
  __shared__ float sred[4][6];
  int w = threadIdx.x >> 6, l = threadIdx.x & 63;
  if (l == 0) {
    #pragma unroll
    for (int j = 0; j < 6; j++) sred[w][j] = vals[j];
  }
  __syncthreads();
  if (threadIdx.x == 0) {
    #pragma unroll
    for (int j = 0; j < 6; j++)
      scal_part[blockIdx.x * 8 + j] = sred[0][j]+sred[1][j]+sred[2][j]+sred[3][j];
  }
}

// ---------------------------------------------------------------------------
// Pass 2: one block of 512 threads (one per object). Reduce the 64 partials,
// decode condensation point, emit packed 12-float table + coward sum.
// ---------------------------------------------------------------------------
__global__ __launch_bounds__(512) void
k_gather(const float* __restrict__ x, const float* __restrict__ beta,
         const unsigned long long* __restrict__ amax_part,
         const unsigned* __restrict__ cnt_part,
         float* __restrict__ ktab, float* __restrict__ cow_sum, int n) {
  int k = threadIdx.x;  // 0..511
  unsigned long long key = 0ull;
  unsigned cnt = 0u;
  #pragma unroll 4
  for (int m = 0; m < MPREP; m++) {
    unsigned long long km = amax_part[(size_t)m * KOBJ + k];
    key = (km > key) ? km : key;
    cnt += cnt_part[(size_t)m * KOBJ + k];
  }
  unsigned idx = ~(unsigned)(key & 0xffffffffull);
  float q_k = __uint_as_float((unsigned)(key >> 32));
  float xv[8], s2 = 0.f;
  #pragma unroll
  for (int c = 0; c < 8; c++) {
    xv[c] = x[(size_t)idx * 8 + c];
    s2 = fmaf(xv[c], xv[c], s2);
  }
  float inv_rep = 1.f / ((float)(n - (int)cnt) + 1e-9f);
  float inv_att = 1.f / ((float)cnt + 1e-9f);
  float* kt = ktab + k * KTW;
  #pragma unroll
  for (int c = 0; c < 8; c++) kt[c] = xv[c];
  kt[8]  = s2;
  kt[9]  = q_k;
  kt[10] = q_k * inv_rep;
  kt[11] = q_k * inv_att;

  float cow = 1.f - beta[idx];
  cow = wave_red_f(cow);
  __shared__ float sred[8];
  if ((threadIdx.x & 63) == 0) sred[threadIdx.x >> 6] = cow;
  __syncthreads();
  if (threadIdx.x == 0) {
    float s = 0.f;
    #pragma unroll
    for (int wv = 0; wv < 8; wv++) s += sred[wv];
    cow_sum[0] = s;
  }
}

// ---------------------------------------------------------------------------
// Pass 3 (hot): one thread per hit, loop over all 512 objects from LDS.
// Per-block partial outputs, no global atomics.
// ---------------------------------------------------------------------------
__global__ __launch_bounds__(256) void
k_pairs(const float* __restrict__ x, const float* __restrict__ beta,
        const int* __restrict__ oid, const float* __restrict__ ktab,
        float* __restrict__ pairs_part, int n) {
  __shared__ float skt[KOBJ * KTW];   // 24 KiB
  for (int t = threadIdx.x; t < KOBJ * KTW; t += 256) skt[t] = ktab[t];
  __syncthreads();

  int i = blockIdx.x * 256 + threadIdx.x;
  float att = 0.f, rep = 0.f, nrep = 0.f;
  if (i < n) {
    const float4* xp = (const float4*)x;
    float4 xa = xp[2 * i];
    float4 xb = xp[2 * i + 1];
    float xi[8] = {xa.x, xa.y, xa.z, xa.w, xb.x, xb.y, xb.z, xb.w};
    float xi2 = 0.f;
    #pragma unroll
    for (int c = 0; c < 8; c++) xi2 = fmaf(xi[c], xi[c], xi2);
    float qi = q_of_beta(beta[i]);
    int own = oid[i] - 1;   // -1 for noise

    if (own >= 0) {
      const float* kt = &skt[own * KTW];
      float dot = 0.f;
      #pragma unroll
      for (int c = 0; c < 8; c++) dot = fmaf(xi[c], kt[c], dot);
      float d2 = fmaxf(xi2 + kt[8] - 2.f * dot, 0.f);
      att = qi * d2 * kt[11];
    }

    #pragma unroll 4
    for (int k = 0; k < KOBJ; k++) {
      const float* kt = &skt[k * KTW];
      float dot = 0.f;
      #pragma unroll
      for (int c = 0; c < 8; c++) dot = fmaf(xi[c], kt[c], dot);
      float d2 = xi2 + kt[8] - 2.f * dot;
      // dist<1 <=> d2<1 (sqrt only on the rare accepted pair)
      if (d2 < 1.f && k != own) {
        float dist = sqrtf(fmaxf(d2, 1e-12f));
        rep = fmaf(qi * (1.f - dist), kt[10], rep);
        nrep += 1.f;
      }
    }
  }

  att = wave_red_f(att);
  rep = wave_red_f(rep);
  nrep = wave_red_f(nrep);
  __shared__ float sred[4][3];
  int w = threadIdx.x >> 6, l = threadIdx.x & 63;
  if (l == 0) { sred[w][0] = att; sred[w][1] = rep; sred[w][2] = nrep; }
  __syncthreads();
  if (threadIdx.x == 0) {
    pairs_part[blockIdx.x * 4 + 0] = sred[0][0]+sred[1][0]+sred[2][0]+sred[3][0];
    pairs_part[blockIdx.x * 4 + 1] = sred[0][1]+sred[1][1]+sred[2][1]+sred[3][1];
    pairs_part[blockIdx.x * 4 + 2] = sred[0][2]+sred[1][2]+sred[2][2]+sred[3][2];
  }
}

// ---------------------------------------------------------------------------
// Pass 4: combine everything.
// ---------------------------------------------------------------------------
__global__ __launch_bounds__(256) void
k_finalize(const float* __restrict__ pairs_part, int nblk,
           const float* __restrict__ scal_part,
           const float* __restrict__ cow_sum, float* __restrict__ out) {
  float v[9] = {0,0,0,0,0,0,0,0,0};  // att, rep, nrep, e, p, pid, noise, ncnt, mcnt
  for (int b = threadIdx.x; b < nblk; b += 256) {
    v[0] += pairs_part[b * 4 + 0];
    v[1] += pairs_part[b * 4 + 1];
    v[2] += pairs_part[b * 4 + 2];
  }
  for (int m = threadIdx.x; m < MPREP; m += 256) {
    #pragma unroll
    for (int j = 0; j < 6; j++) v[3 + j] += scal_part[m * 8 + j];
  }
  #pragma unroll
  for (int j = 0; j < 9; j++) v[j] = wave_red_f(v[j]);
  __shared__ float sred[4][9];
  int w = threadIdx.x >> 6, l = threadIdx.x & 63;
  if (l == 0) {
    #pragma unroll
    for (int j = 0; j < 9; j++) sred[w][j] = v[j];
  }
  __syncthreads();
  if (threadIdx.x == 0) {
    float t[9];
    #pragma unroll
    for (int j = 0; j < 9; j++) t[j] = sred[0][j]+sred[1][j]+sred[2][j]+sred[3][j];
    float v_att  = t[0] / (float)KOBJ;
    float v_rep  = t[1] / (float)KOBJ;
    float n_rep  = t[2];
    float l_cow  = cow_sum[0] / (float)KOBJ;
    float l_noise = t[6] / t[7];
    float oc = v_att + v_rep + l_cow + l_noise;
    float nm = t[8];
    float e_loss  = t[3] / nm;
    float p_loss  = t[4] / (nm * 3.f);
    float pid_loss = t[5] / nm;
    out[0] = v_att;
    out[1] = v_rep;
    out[2] = l_cow;
    out[3] = l_noise;
    out[4] = n_rep;
    out[5] = oc;
    out[6] = e_loss;
    out[7] = p_loss;
    out[8] = pid_loss;
    out[9] = oc + e_loss + p_loss + pid_loss;
  }
}

extern "C" void kernel_launch(void* const* d_in, const int* in_sizes, int n_in,
                              void* d_out, int out_size, void* d_ws, size_t ws_size,
                              hipStream_t stream) {
  const float* beta   = (const float*)d_in[0];
  const float* x      = (const float*)d_in[1];
  const int*   oid    = (const int*)d_in[2];
  const float* energy = (const float*)d_in[3];
  const float* eph    = (const float*)d_in[4];
  const float* mom    = (const float*)d_in[5];
  const float* mph    = (const float*)d_in[6];
  const float* logits = (const float*)d_in[7];
  const int*   pid    = (const int*)d_in[8];
  float* out = (float*)d_out;
  const int n = in_sizes[0];
  const int nblk = (n + 255) / 256;

  char* base = (char*)d_ws;
  size_t off = 0;
  unsigned long long* amax_part = (unsigned long long*)(base + off); off += (size_t)MPREP * KOBJ * 8;
  unsigned* cnt_part = (unsigned*)(base + off);                      off += (size_t)MPREP * KOBJ * 4;
  float* scal_part   = (float*)(base + off);                         off += (size_t)MPREP * 8 * 4;
  float* ktab        = (float*)(base + off);                         off += (size_t)KOBJ * KTW * 4;
  float* pairs_part  = (float*)(base + off);                         off += (size_t)nblk * 4 * 4;
  float* cow_sum     = (float*)(base + off);                         off += 4;

  k_prep<<<MPREP, 256, 0, stream>>>(beta, oid, energy, eph, mom, mph, logits, pid,
                                    amax_part, cnt_part, scal_part, n);
  k_gather<<<1, 512, 0, stream>>>(x, beta, amax_part, cnt_part, ktab, cow_sum, n);
  k_pairs<<<nblk, 256, 0, stream>>>(x, beta, oid, ktab, pairs_part, n);
  k_finalize<<<1, 256, 0, stream>>>(pairs_part, nblk, scal_part, cow_sum, out);
}

// Round 3
// 136.492 us; speedup vs baseline: 2.5553x; 1.0518x over previous
//
#include <hip/hip_runtime.h>
#include <math.h>

#define KOBJ 512
#define KTW 12    // packed row: x[8], xk2, w_rep=qk*inv_nrep, w_att=qk*inv_att, pad
#define TK 128    // k-tile per block in k_pairs
#define NTILE (KOBJ / TK)

__device__ __forceinline__ float wave_red_f(float v) {
  #pragma unroll
  for (int off = 32; off > 0; off >>= 1) v += __shfl_down(v, off, 64);
  return v;
}

// fast atanh(b)^2 + 1 ; b in (0, 0.96]
__device__ __forceinline__ float q_of_beta(float b) {
  float a = 0.5f * __logf((1.f + b) / (1.f - b));
  return fmaf(a, a, 1.f);
}

// ---------------------------------------------------------------------------
// Pass 1: M persistent blocks (M<=256, ws-budgeted). LDS-aggregated per-object
// argmax(q)/counts flushed as per-block partial tables; payload losses reduced
// per block. Zero global atomics.
// ---------------------------------------------------------------------------
__global__ __launch_bounds__(256) void
k_prep(const float* __restrict__ beta, const int* __restrict__ oid,
       const float* __restrict__ energy, const float* __restrict__ eph,
       const float* __restrict__ mom, const float* __restrict__ mph,
       const float* __restrict__ logits, const int* __restrict__ pid,
       unsigned long long* __restrict__ amax_part,
       unsigned* __restrict__ cnt_part,
       float* __restrict__ scal_part, int n, int M) {
  __shared__ unsigned long long lmax[KOBJ];
  __shared__ unsigned lcnt[KOBJ];
  for (int t = threadIdx.x; t < KOBJ; t += 256) { lmax[t] = 0ull; lcnt[t] = 0u; }
  __syncthreads();

  float e_t = 0.f, p_t = 0.f, pid_t = 0.f, noise_t = 0.f, ncnt = 0.f, mcnt = 0.f;
  for (int i = blockIdx.x * 256 + threadIdx.x; i < n; i += M * 256) {
    float b = beta[i];
    int o = oid[i];
    if (o > 0) {
      float q = q_of_beta(b);
      // pack (q bits | ~i): max-q wins, ties -> smallest index (argmax semantics)
      unsigned long long key = ((unsigned long long)__float_as_uint(q) << 32)
                             | (unsigned long long)(unsigned)(~(unsigned)i);
      atomicMax(&lmax[o - 1], key);
      atomicAdd(&lcnt[o - 1], 1u);
      mcnt += 1.f;
      float de = energy[i] - eph[i];
      e_t = fmaf(de, de, e_t);
      float p0 = mom[3*i+0] - mph[3*i+0];
      float p1 = mom[3*i+1] - mph[3*i+1];
      float p2 = mom[3*i+2] - mph[3*i+2];
      p_t = fmaf(p0, p0, p_t); p_t = fmaf(p1, p1, p_t); p_t = fmaf(p2, p2, p_t);
      const float* lg = logits + 6*i;
      float l0=lg[0], l1=lg[1], l2=lg[2], l3=lg[3], l4=lg[4], l5=lg[5];
      float mx = fmaxf(fmaxf(fmaxf(l0,l1),fmaxf(l2,l3)), fmaxf(l4,l5));
      float s = __expf(l0-mx)+__expf(l1-mx)+__expf(l2-mx)
              + __expf(l3-mx)+__expf(l4-mx)+__expf(l5-mx);
      int pc = pid[i];
      float lp = (pc==0)?l0:(pc==1)?l1:(pc==2)?l2:(pc==3)?l3:(pc==4)?l4:l5;
      pid_t += mx + __logf(s) - lp;
    } else {
      noise_t += b;
      ncnt += 1.f;
    }
  }
  __syncthreads();

  for (int t = threadIdx.x; t < KOBJ; t += 256) {
    amax_part[(size_t)blockIdx.x * KOBJ + t] = lmax[t];
    cnt_part[(size_t)blockIdx.x * KOBJ + t]  = lcnt[t];
  }

  float vals[6] = {e_t, p_t, pid_t, noise_t, ncnt, mcnt};
  #pragma unroll
  for (int j = 0; j < 6; j++) vals[j] = wave_red_f(vals[j]);
  __shared__ float sred[4][6];
  int w = threadIdx.x >> 6, l = threadIdx.x & 63;
  if (l == 0) {
    #pragma unroll
    for (int j = 0; j < 6; j++) sred[w][j] = vals[j];
  }
  __syncthreads();
  if (threadIdx.x == 0) {
    #pragma unroll
    for (int j = 0; j < 6; j++)
      scal_part[blockIdx.x * 8 + j] = sred[0][j]+sred[1][j]+sred[2][j]+sred[3][j];
  }
}

// ---------------------------------------------------------------------------
// Pass 2: 8 blocks x 256 threads. Block b owns objects [b*64,(b+1)*64);
// thread = (m_chunk 0..3, object). Reduce M partials, decode condensation
// point, emit packed 12-float row + per-block coward partial.
// ---------------------------------------------------------------------------
__global__ __launch_bounds__(256) void
k_gather(const float* __restrict__ x, const float* __restrict__ beta,
         const unsigned long long* __restrict__ amax_part,
         const unsigned* __restrict__ cnt_part,
         float* __restrict__ ktab, float* __restrict__ cow_part, int n, int M) {
  int ko = threadIdx.x & 63;          // object within block
  int chunk = threadIdx.x >> 6;       // 0..3 m-chunk
  int k = blockIdx.x * 64 + ko;       // global object id - 1
  int m0 = (chunk * M) >> 2, m1 = ((chunk + 1) * M) >> 2;

  unsigned long long key = 0ull;
  unsigned cnt = 0u;
  for (int m = m0; m < m1; m++) {
    unsigned long long km = amax_part[(size_t)m * KOBJ + k];
    key = (km > key) ? km : key;
    cnt += cnt_part[(size_t)m * KOBJ + k];
  }
  __shared__ unsigned long long skey[4][64];
  __shared__ unsigned scnt[4][64];
  skey[chunk][ko] = key;
  scnt[chunk][ko] = cnt;
  __syncthreads();

  float cow = 0.f;
  if (chunk == 0) {
    #pragma unroll
    for (int c = 1; c < 4; c++) {
      unsigned long long kc = skey[c][ko];
      key = (kc > key) ? kc : key;
      cnt += scnt[c][ko];
    }
    unsigned idx = ~(unsigned)(key & 0xffffffffull);
    float q_k = __uint_as_float((unsigned)(key >> 32));
    const float4* xp = (const float4*)x;
    float4 xa = xp[2 * (size_t)idx];
    float4 xb = xp[2 * (size_t)idx + 1];
    float xv[8] = {xa.x, xa.y, xa.z, xa.w, xb.x, xb.y, xb.z, xb.w};
    float s2 = 0.f;
    #pragma unroll
    for (int c = 0; c < 8; c++) s2 = fmaf(xv[c], xv[c], s2);
    float* kt = ktab + (size_t)k * KTW;
    #pragma unroll
    for (int c = 0; c < 8; c++) kt[c] = xv[c];
    kt[8]  = s2;
    kt[9]  = q_k / ((float)(n - (int)cnt) + 1e-9f);   // w_rep
    kt[10] = q_k / ((float)cnt + 1e-9f);              // w_att
    kt[11] = 0.f;
    cow = 1.f - beta[idx];
    cow = wave_red_f(cow);   // chunk==0 threads are exactly wave 0
    if (ko == 0) cow_part[blockIdx.x] = cow;
  }
}

// ---------------------------------------------------------------------------
// Pass 3 (hot): 2D grid (hit-blocks x 4 k-tiles). Thread = one hit, loop over
// TK=128 objects from a 6 KB LDS slice. Own-object term subtracted after the
// loop; attractive term computed in the owning tile only.
// ---------------------------------------------------------------------------
__global__ __launch_bounds__(256) void
k_pairs(const float* __restrict__ x, const float* __restrict__ beta,
        const int* __restrict__ oid, const float* __restrict__ ktab,
        float* __restrict__ pairs_part, int n) {
  __shared__ float skt[TK * KTW];   // 6 KiB
  const int tile0 = blockIdx.y * TK;
  for (int t = threadIdx.x; t < TK * KTW; t += 256)
    skt[t] = ktab[(size_t)tile0 * KTW + t];
  __syncthreads();

  int i = blockIdx.x * 256 + threadIdx.x;
  float att = 0.f, rep = 0.f, nrep = 0.f;
  if (i < n) {
    const float4* xp = (const float4*)x;
    float4 xa = xp[2 * (size_t)i];
    float4 xb = xp[2 * (size_t)i + 1];
    float xi[8] = {xa.x, xa.y, xa.z, xa.w, xb.x, xb.y, xb.z, xb.w};
    float yi[8], xi2 = 0.f;
    #pragma unroll
    for (int c = 0; c < 8; c++) {
      xi2 = fmaf(xi[c], xi[c], xi2);
      yi[c] = -2.f * xi[c];
    }
    float qi = q_of_beta(beta[i]);

    #pragma unroll 4
    for (int k = 0; k < TK; k++) {
      const float* kt = &skt[k * KTW];
      float d2 = xi2 + kt[8];
      #pragma unroll
      for (int c = 0; c < 8; c++) d2 = fmaf(yi[c], kt[c], d2);
      // dist<1 <=> d2<1 ; sqrt only on the rare accepted pair (~1%/wave-iter)
      if (d2 < 1.f) {
        float dist = sqrtf(fmaxf(d2, 1e-12f));
        rep = fmaf(qi * (1.f - dist), kt[9], rep);
        nrep += 1.f;
      }
    }

    int ko = oid[i] - 1 - tile0;   // own object within this tile (or out of range)
    if (ko >= 0 && ko < TK) {
      const float* kt = &skt[ko * KTW];
      float d2 = xi2 + kt[8];
      #pragma unroll
      for (int c = 0; c < 8; c++) d2 = fmaf(yi[c], kt[c], d2);
      att = qi * fmaxf(d2, 0.f) * kt[10];
      if (d2 < 1.f) {   // undo the in-loop repulsive contribution of own
        float dist = sqrtf(fmaxf(d2, 1e-12f));
        float t = qi * (1.f - dist);
        rep = fmaf(-t, kt[9], rep);
        nrep -= 1.f;
      }
    }
  }

  att = wave_red_f(att);
  rep = wave_red_f(rep);
  nrep = wave_red_f(nrep);
  __shared__ float sred[4][3];
  int w = threadIdx.x >> 6, l = threadIdx.x & 63;
  if (l == 0) { sred[w][0] = att; sred[w][1] = rep; sred[w][2] = nrep; }
  __syncthreads();
  if (threadIdx.x == 0) {
    int bid = blockIdx.y * gridDim.x + blockIdx.x;
    pairs_part[bid * 4 + 0] = sred[0][0]+sred[1][0]+sred[2][0]+sred[3][0];
    pairs_part[bid * 4 + 1] = sred[0][1]+sred[1][1]+sred[2][1]+sred[3][1];
    pairs_part[bid * 4 + 2] = sred[0][2]+sred[1][2]+sred[2][2]+sred[3][2];
  }
}

// ---------------------------------------------------------------------------
// Pass 4: combine everything.
// ---------------------------------------------------------------------------
__global__ __launch_bounds__(256) void
k_finalize(const float* __restrict__ pairs_part, int nblk_tot,
           const float* __restrict__ scal_part, int M,
           const float* __restrict__ cow_part, float* __restrict__ out) {
  float v[9] = {0,0,0,0,0,0,0,0,0};  // att, rep, nrep, e, p, pid, noise, ncnt, mcnt
  for (int b = threadIdx.x; b < nblk_tot; b += 256) {
    v[0] += pairs_part[b * 4 + 0];
    v[1] += pairs_part[b * 4 + 1];
    v[2] += pairs_part[b * 4 + 2];
  }
  for (int m = threadIdx.x; m < M; m += 256) {
    #pragma unroll
    for (int j = 0; j < 6; j++) v[3 + j] += scal_part[m * 8 + j];
  }
  #pragma unroll
  for (int j = 0; j < 9; j++) v[j] = wave_red_f(v[j]);
  __shared__ float sred[4][9];
  int w = threadIdx.x >> 6, l = threadIdx.x & 63;
  if (l == 0) {
    #pragma unroll
    for (int j = 0; j < 9; j++) sred[w][j] = v[j];
  }
  __syncthreads();
  if (threadIdx.x == 0) {
    float t[9];
    #pragma unroll
    for (int j = 0; j < 9; j++) t[j] = sred[0][j]+sred[1][j]+sred[2][j]+sred[3][j];
    float cow = cow_part[0]+cow_part[1]+cow_part[2]+cow_part[3]
              + cow_part[4]+cow_part[5]+cow_part[6]+cow_part[7];
    float v_att  = t[0] / (float)KOBJ;
    float v_rep  = t[1] / (float)KOBJ;
    float n_rep  = t[2];
    float l_cow  = cow / (float)KOBJ;
    float l_noise = t[6] / t[7];
    float oc = v_att + v_rep + l_cow + l_noise;
    float nm = t[8];
    float e_loss  = t[3] / nm;
    float p_loss  = t[4] / (nm * 3.f);
    float pid_loss = t[5] / nm;
    out[0] = v_att;
    out[1] = v_rep;
    out[2] = l_cow;
    out[3] = l_noise;
    out[4] = n_rep;
    out[5] = oc;
    out[6] = e_loss;
    out[7] = p_loss;
    out[8] = pid_loss;
    out[9] = oc + e_loss + p_loss + pid_loss;
  }
}

extern "C" void kernel_launch(void* const* d_in, const int* in_sizes, int n_in,
                              void* d_out, int out_size, void* d_ws, size_t ws_size,
                              hipStream_t stream) {
  const float* beta   = (const float*)d_in[0];
  const float* x      = (const float*)d_in[1];
  const int*   oid    = (const int*)d_in[2];
  const float* energy = (const float*)d_in[3];
  const float* eph    = (const float*)d_in[4];
  const float* mom    = (const float*)d_in[5];
  const float* mph    = (const float*)d_in[6];
  const float* logits = (const float*)d_in[7];
  const int*   pid    = (const int*)d_in[8];
  float* out = (float*)d_out;
  const int n = in_sizes[0];
  const int nblk = (n + 255) / 256;
  const int nblk_tot = nblk * NTILE;

  char* base = (char*)d_ws;
  size_t off = 0;
  float* ktab       = (float*)(base + off); off += (size_t)KOBJ * KTW * 4;
  float* cow_part   = (float*)(base + off); off += 8 * 4;
  float* pairs_part = (float*)(base + off); off += (size_t)nblk_tot * 4 * 4;
  off = (off + 255) & ~(size_t)255;

  // budget the per-block partial tables from remaining workspace
  size_t per_m = (size_t)KOBJ * 8 + (size_t)KOBJ * 4 + 32;
  long long avail = (long long)ws_size - (long long)off;
  int M = (int)(avail / (long long)per_m);
  if (M > 256) M = 256;
  M &= ~3;                 // multiple of 4 for the gather chunk split
  if (M < 4) M = 4;        // (ws assumed at least ~100 KB)

  unsigned long long* amax_part = (unsigned long long*)(base + off); off += (size_t)M * KOBJ * 8;
  unsigned* cnt_part = (unsigned*)(base + off);                      off += (size_t)M * KOBJ * 4;
  float* scal_part   = (float*)(base + off);                         off += (size_t)M * 8 * 4;

  k_prep<<<M, 256, 0, stream>>>(beta, oid, energy, eph, mom, mph, logits, pid,
                                amax_part, cnt_part, scal_part, n, M);
  k_gather<<<8, 256, 0, stream>>>(x, beta, amax_part, cnt_part, ktab, cow_part, n, M);
  k_pairs<<<dim3(nblk, NTILE), 256, 0, stream>>>(x, beta, oid, ktab, pairs_part, n);
  k_finalize<<<1, 256, 0, stream>>>(pairs_part, nblk_tot, scal_part, M, cow_part, out);
}

// Round 4
// 127.443 us; speedup vs baseline: 2.7367x; 1.0710x over previous
//
#include <hip/hip_runtime.h>
#include <math.h>

#define KOBJ 512
#define KTW 12    // packed row: x[8], xk2, w_rep=qk*inv_nrep, w_att=qk*inv_att, pad
#define TK 64     // k-tile per block in k_pairs
#define NTILE (KOBJ / TK)   // 8
#define HB 4      // hits per thread (register blocking)
#define HCH (256 * HB)      // 1024 hits per block

__device__ __forceinline__ float wave_red_f(float v) {
  #pragma unroll
  for (int off = 32; off > 0; off >>= 1) v += __shfl_down(v, off, 64);
  return v;
}

// fast atanh(b)^2 + 1 ; b in (0, 0.96]
__device__ __forceinline__ float q_of_beta(float b) {
  float a = 0.5f * __logf((1.f + b) / (1.f - b));
  return fmaf(a, a, 1.f);
}

// ---------------------------------------------------------------------------
// Pass 1: M persistent blocks. LDS-aggregated per-object argmax(q)/counts
// flushed as per-block partial tables; payload losses reduced per block.
// Zero global atomics.
// ---------------------------------------------------------------------------
__global__ __launch_bounds__(256) void
k_prep(const float* __restrict__ beta, const int* __restrict__ oid,
       const float* __restrict__ energy, const float* __restrict__ eph,
       const float* __restrict__ mom, const float* __restrict__ mph,
       const float* __restrict__ logits, const int* __restrict__ pid,
       unsigned long long* __restrict__ amax_part,
       unsigned* __restrict__ cnt_part,
       float* __restrict__ scal_part, int n, int M) {
  __shared__ unsigned long long lmax[KOBJ];
  __shared__ unsigned lcnt[KOBJ];
  for (int t = threadIdx.x; t < KOBJ; t += 256) { lmax[t] = 0ull; lcnt[t] = 0u; }
  __syncthreads();

  float e_t = 0.f, p_t = 0.f, pid_t = 0.f, noise_t = 0.f, ncnt = 0.f, mcnt = 0.f;
  for (int i = blockIdx.x * 256 + threadIdx.x; i < n; i += M * 256) {
    float b = beta[i];
    int o = oid[i];
    if (o > 0) {
      float q = q_of_beta(b);
      // pack (q bits | ~i): max-q wins, ties -> smallest index (argmax semantics)
      unsigned long long key = ((unsigned long long)__float_as_uint(q) << 32)
                             | (unsigned long long)(unsigned)(~(unsigned)i);
      atomicMax(&lmax[o - 1], key);
      atomicAdd(&lcnt[o - 1], 1u);
      mcnt += 1.f;
      float de = energy[i] - eph[i];
      e_t = fmaf(de, de, e_t);
      float p0 = mom[3*i+0] - mph[3*i+0];
      float p1 = mom[3*i+1] - mph[3*i+1];
      float p2 = mom[3*i+2] - mph[3*i+2];
      p_t = fmaf(p0, p0, p_t); p_t = fmaf(p1, p1, p_t); p_t = fmaf(p2, p2, p_t);
      const float* lg = logits + 6*i;
      float l0=lg[0], l1=lg[1], l2=lg[2], l3=lg[3], l4=lg[4], l5=lg[5];
      float mx = fmaxf(fmaxf(fmaxf(l0,l1),fmaxf(l2,l3)), fmaxf(l4,l5));
      float s = __expf(l0-mx)+__expf(l1-mx)+__expf(l2-mx)
              + __expf(l3-mx)+__expf(l4-mx)+__expf(l5-mx);
      int pc = pid[i];
      float lp = (pc==0)?l0:(pc==1)?l1:(pc==2)?l2:(pc==3)?l3:(pc==4)?l4:l5;
      pid_t += mx + __logf(s) - lp;
    } else {
      noise_t += b;
      ncnt += 1.f;
    }
  }
  __syncthreads();

  for (int t = threadIdx.x; t < KOBJ; t += 256) {
    amax_part[(size_t)blockIdx.x * KOBJ + t] = lmax[t];
    cnt_part[(size_t)blockIdx.x * KOBJ + t]  = lcnt[t];
  }

  float vals[6] = {e_t, p_t, pid_t, noise_t, ncnt, mcnt};
  #pragma unroll
  for (int j = 0; j < 6; j++) vals[j] = wave_red_f(vals[j]);
  __shared__ float sred[4][6];
  int w = threadIdx.x >> 6, l = threadIdx.x & 63;
  if (l == 0) {
    #pragma unroll
    for (int j = 0; j < 6; j++) sred[w][j] = vals[j];
  }
  __syncthreads();
  if (threadIdx.x == 0) {
    #pragma unroll
    for (int j = 0; j < 6; j++)
      scal_part[blockIdx.x * 8 + j] = sred[0][j]+sred[1][j]+sred[2][j]+sred[3][j];
  }
}

// ---------------------------------------------------------------------------
// Pass 2: 8 blocks x 256 threads. Block b owns objects [b*64,(b+1)*64);
// thread = (m_chunk 0..3, object). Reduce M partials, decode condensation
// point, emit packed 12-float row + per-block coward partial.
// ---------------------------------------------------------------------------
__global__ __launch_bounds__(256) void
k_gather(const float* __restrict__ x, const float* __restrict__ beta,
         const unsigned long long* __restrict__ amax_part,
         const unsigned* __restrict__ cnt_part,
         float* __restrict__ ktab, float* __restrict__ cow_part, int n, int M) {
  int ko = threadIdx.x & 63;          // object within block
  int chunk = threadIdx.x >> 6;       // 0..3 m-chunk
  int k = blockIdx.x * 64 + ko;       // global object id - 1
  int m0 = (chunk * M) >> 2, m1 = ((chunk + 1) * M) >> 2;

  unsigned long long key = 0ull;
  unsigned cnt = 0u;
  for (int m = m0; m < m1; m++) {
    unsigned long long km = amax_part[(size_t)m * KOBJ + k];
    key = (km > key) ? km : key;
    cnt += cnt_part[(size_t)m * KOBJ + k];
  }
  __shared__ unsigned long long skey[4][64];
  __shared__ unsigned scnt[4][64];
  skey[chunk][ko] = key;
  scnt[chunk][ko] = cnt;
  __syncthreads();

  float cow = 0.f;
  if (chunk == 0) {
    #pragma unroll
    for (int c = 1; c < 4; c++) {
      unsigned long long kc = skey[c][ko];
      key = (kc > key) ? kc : key;
      cnt += scnt[c][ko];
    }
    unsigned idx = ~(unsigned)(key & 0xffffffffull);
    float q_k = __uint_as_float((unsigned)(key >> 32));
    const float4* xp = (const float4*)x;
    float4 xa = xp[2 * (size_t)idx];
    float4 xb = xp[2 * (size_t)idx + 1];
    float xv[8] = {xa.x, xa.y, xa.z, xa.w, xb.x, xb.y, xb.z, xb.w};
    float s2 = 0.f;
    #pragma unroll
    for (int c = 0; c < 8; c++) s2 = fmaf(xv[c], xv[c], s2);
    float* kt = ktab + (size_t)k * KTW;
    #pragma unroll
    for (int c = 0; c < 8; c++) kt[c] = xv[c];
    kt[8]  = s2;
    kt[9]  = q_k / ((float)(n - (int)cnt) + 1e-9f);   // w_rep
    kt[10] = q_k / ((float)cnt + 1e-9f);              // w_att
    kt[11] = 0.f;
    cow = 1.f - beta[idx];
    cow = wave_red_f(cow);   // chunk==0 threads are exactly wave 0
    if (ko == 0) cow_part[blockIdx.x] = cow;
  }
}

// ---------------------------------------------------------------------------
// Pass 3 (hot): 2D grid (118 hit-blocks x 8 k-tiles). Each thread holds HB=4
// hits in registers and loops over TK=64 objects from a 3 KB LDS slice --
// each LDS row read is reused for 4 pairs (register blocking). Own-object
// term subtracted after the loop; attractive term in the owning tile only.
// ---------------------------------------------------------------------------
__global__ __launch_bounds__(256) void
k_pairs(const float* __restrict__ x, const float* __restrict__ beta,
        const int* __restrict__ oid, const float* __restrict__ ktab,
        float* __restrict__ pairs_part, int n) {
  __shared__ float skt[TK * KTW];   // 3 KiB
  const int tile0 = blockIdx.y * TK;
  for (int t = threadIdx.x; t < TK * KTW; t += 256)
    skt[t] = ktab[(size_t)tile0 * KTW + t];
  __syncthreads();

  // load HB hits into registers
  float yi[HB][8], b2[HB], qi[HB];
  int own[HB];
  const float4* xp = (const float4*)x;
  #pragma unroll
  for (int h = 0; h < HB; h++) {
    int i = blockIdx.x * HCH + h * 256 + threadIdx.x;
    if (i < n) {
      float4 xa = xp[2 * (size_t)i];
      float4 xb = xp[2 * (size_t)i + 1];
      float xi[8] = {xa.x, xa.y, xa.z, xa.w, xb.x, xb.y, xb.z, xb.w};
      float s = 0.f;
      #pragma unroll
      for (int c = 0; c < 8; c++) {
        s = fmaf(xi[c], xi[c], s);
        yi[h][c] = -2.f * xi[c];
      }
      b2[h] = s;
      qi[h] = q_of_beta(beta[i]);
      own[h] = oid[i] - 1 - tile0;   // own object within tile (or out of range)
    } else {
      #pragma unroll
      for (int c = 0; c < 8; c++) yi[h][c] = 0.f;
      b2[h] = 3.f;                   // d2 = 3 + xk2 >= 3 : never passes hinge
      qi[h] = 0.f;
      own[h] = -1;
    }
  }

  float att = 0.f, rep = 0.f, nrep = 0.f;
  #pragma unroll 2
  for (int k = 0; k < TK; k++) {
    const float* kt = &skt[k * KTW];
    float k0 = kt[0], k1 = kt[1], k2 = kt[2], k3 = kt[3];
    float k4 = kt[4], k5 = kt[5], k6 = kt[6], k7 = kt[7];
    float s2 = kt[8], wr = kt[9];
    #pragma unroll
    for (int h = 0; h < HB; h++) {
      float d2 = b2[h] + s2;
      d2 = fmaf(yi[h][0], k0, d2);
      d2 = fmaf(yi[h][1], k1, d2);
      d2 = fmaf(yi[h][2], k2, d2);
      d2 = fmaf(yi[h][3], k3, d2);
      d2 = fmaf(yi[h][4], k4, d2);
      d2 = fmaf(yi[h][5], k5, d2);
      d2 = fmaf(yi[h][6], k6, d2);
      d2 = fmaf(yi[h][7], k7, d2);
      // dist<1 <=> d2<1 ; sqrt only on the rare accepted pair
      if (d2 < 1.f) {
        float dist = sqrtf(fmaxf(d2, 1e-12f));
        rep = fmaf(qi[h] * (1.f - dist), wr, rep);
        nrep += 1.f;
      }
    }
  }

  // own-object handling: attractive term + undo in-loop repulsive contribution
  #pragma unroll
  for (int h = 0; h < HB; h++) {
    int ko = own[h];
    if (ko >= 0 && ko < TK) {
      const float* kt = &skt[ko * KTW];
      float d2 = b2[h] + kt[8];
      #pragma unroll
      for (int c = 0; c < 8; c++) d2 = fmaf(yi[h][c], kt[c], d2);
      att = fmaf(qi[h] * fmaxf(d2, 0.f), kt[10], att);
      if (d2 < 1.f) {
        float dist = sqrtf(fmaxf(d2, 1e-12f));
        rep = fmaf(-qi[h] * (1.f - dist), kt[9], rep);
        nrep -= 1.f;
      }
    }
  }

  att = wave_red_f(att);
  rep = wave_red_f(rep);
  nrep = wave_red_f(nrep);
  __shared__ float sred[4][3];
  int w = threadIdx.x >> 6, l = threadIdx.x & 63;
  if (l == 0) { sred[w][0] = att; sred[w][1] = rep; sred[w][2] = nrep; }
  __syncthreads();
  if (threadIdx.x == 0) {
    int bid = blockIdx.y * gridDim.x + blockIdx.x;
    pairs_part[bid * 4 + 0] = sred[0][0]+sred[1][0]+sred[2][0]+sred[3][0];
    pairs_part[bid * 4 + 1] = sred[0][1]+sred[1][1]+sred[2][1]+sred[3][1];
    pairs_part[bid * 4 + 2] = sred[0][2]+sred[1][2]+sred[2][2]+sred[3][2];
  }
}

// ---------------------------------------------------------------------------
// Pass 4: combine everything.
// ---------------------------------------------------------------------------
__global__ __launch_bounds__(256) void
k_finalize(const float* __restrict__ pairs_part, int nblk_tot,
           const float* __restrict__ scal_part, int M,
           const float* __restrict__ cow_part, float* __restrict__ out) {
  float v[9] = {0,0,0,0,0,0,0,0,0};  // att, rep, nrep, e, p, pid, noise, ncnt, mcnt
  for (int b = threadIdx.x; b < nblk_tot; b += 256) {
    v[0] += pairs_part[b * 4 + 0];
    v[1] += pairs_part[b * 4 + 1];
    v[2] += pairs_part[b * 4 + 2];
  }
  for (int m = threadIdx.x; m < M; m += 256) {
    #pragma unroll
    for (int j = 0; j < 6; j++) v[3 + j] += scal_part[m * 8 + j];
  }
  #pragma unroll
  for (int j = 0; j < 9; j++) v[j] = wave_red_f(v[j]);
  __shared__ float sred[4][9];
  int w = threadIdx.x >> 6, l = threadIdx.x & 63;
  if (l == 0) {
    #pragma unroll
    for (int j = 0; j < 9; j++) sred[w][j] = v[j];
  }
  __syncthreads();
  if (threadIdx.x == 0) {
    float t[9];
    #pragma unroll
    for (int j = 0; j < 9; j++) t[j] = sred[0][j]+sred[1][j]+sred[2][j]+sred[3][j];
    float cow = cow_part[0]+cow_part[1]+cow_part[2]+cow_part[3]
              + cow_part[4]+cow_part[5]+cow_part[6]+cow_part[7];
    float v_att  = t[0] / (float)KOBJ;
    float v_rep  = t[1] / (float)KOBJ;
    float n_rep  = t[2];
    float l_cow  = cow / (float)KOBJ;
    float l_noise = t[6] / t[7];
    float oc = v_att + v_rep + l_cow + l_noise;
    float nm = t[8];
    float e_loss  = t[3] / nm;
    float p_loss  = t[4] / (nm * 3.f);
    float pid_loss = t[5] / nm;
    out[0] = v_att;
    out[1] = v_rep;
    out[2] = l_cow;
    out[3] = l_noise;
    out[4] = n_rep;
    out[5] = oc;
    out[6] = e_loss;
    out[7] = p_loss;
    out[8] = pid_loss;
    out[9] = oc + e_loss + p_loss + pid_loss;
  }
}

extern "C" void kernel_launch(void* const* d_in, const int* in_sizes, int n_in,
                              void* d_out, int out_size, void* d_ws, size_t ws_size,
                              hipStream_t stream) {
  const float* beta   = (const float*)d_in[0];
  const float* x      = (const float*)d_in[1];
  const int*   oid    = (const int*)d_in[2];
  const float* energy = (const float*)d_in[3];
  const float* eph    = (const float*)d_in[4];
  const float* mom    = (const float*)d_in[5];
  const float* mph    = (const float*)d_in[6];
  const float* logits = (const float*)d_in[7];
  const int*   pid    = (const int*)d_in[8];
  float* out = (float*)d_out;
  const int n = in_sizes[0];
  const int nhb = (n + HCH - 1) / HCH;     // hit-blocks
  const int nblk_tot = nhb * NTILE;

  char* base = (char*)d_ws;
  size_t off = 0;
  float* ktab       = (float*)(base + off); off += (size_t)KOBJ * KTW * 4;
  float* cow_part   = (float*)(base + off); off += 8 * 4;
  float* pairs_part = (float*)(base + off); off += (size_t)nblk_tot * 4 * 4;
  off = (off + 255) & ~(size_t)255;

  // budget the per-block partial tables from remaining workspace
  size_t per_m = (size_t)KOBJ * 8 + (size_t)KOBJ * 4 + 32;
  long long avail = (long long)ws_size - (long long)off;
  int M = (int)(avail / (long long)per_m);
  if (M > 256) M = 256;
  M &= ~3;                 // multiple of 4 for the gather chunk split
  if (M < 4) M = 4;

  unsigned long long* amax_part = (unsigned long long*)(base + off); off += (size_t)M * KOBJ * 8;
  unsigned* cnt_part = (unsigned*)(base + off);                      off += (size_t)M * KOBJ * 4;
  float* scal_part   = (float*)(base + off);                         off += (size_t)M * 8 * 4;

  k_prep<<<M, 256, 0, stream>>>(beta, oid, energy, eph, mom, mph, logits, pid,
                                amax_part, cnt_part, scal_part, n, M);
  k_gather<<<8, 256, 0, stream>>>(x, beta, amax_part, cnt_part, ktab, cow_part, n, M);
  k_pairs<<<dim3(nhb, NTILE), 256, 0, stream>>>(x, beta, oid, ktab, pairs_part, n);
  k_finalize<<<1, 256, 0, stream>>>(pairs_part, nblk_tot, scal_part, M, cow_part, out);
}